// Round 1
// baseline (407.605 us; speedup 1.0000x reference)
//
#include <hip/hip_runtime.h>

#define NN 768
#define FD 256
#define HD 128
#define NBLK 300

__device__ __forceinline__ float relu(float x) { return x > 0.f ? x : 0.f; }
__device__ __forceinline__ void fma4(float4& a, float s, float4 v) {
    a.x = fmaf(s, v.x, a.x); a.y = fmaf(s, v.y, a.y);
    a.z = fmaf(s, v.z, a.z); a.w = fmaf(s, v.w, a.w);
}
__device__ __forceinline__ float rdot(float4 a, float4 b, float4 w) {
    float s = relu(a.x + b.x) * w.x;
    s = fmaf(relu(a.y + b.y), w.y, s);
    s = fmaf(relu(a.z + b.z), w.z, s);
    s = fmaf(relu(a.w + b.w), w.w, s);
    return s;
}

// Per-stage LDS layouts, unioned (max = S4: 35328 B -> 2 blocks/CU fits 160 KB).
struct S1mem { float xs[3][FD]; float ts[HD]; float sdi[4]; };
struct S2mem { float adjT[NN][4]; float part[8][3][HD]; float gs[3][HD]; };
struct S4mem { float pi[32][68]; float qi[32][68]; float pj[32][68]; float qj[32][68]; float w2s[HD]; };
union SMem { S1mem s1; S2mem s2; S4mem s4; };

// Manual grid barrier. Safe: grid=300 blocks, 256thr, 35.3KB LDS, <=128 VGPR
// (launch_bounds) -> 2 blocks/CU capacity = 512 slots >= 300, all co-resident.
// Counters zeroed by captured hipMemsetAsync before launch.
__device__ __forceinline__ void gsync(int* cnt) {
    __threadfence();             // release: flush this block's writes to device scope
    __syncthreads();
    if (threadIdx.x == 0) {
        atomicAdd(cnt, 1);       // device-scope by default
        while (__hip_atomic_load(cnt, __ATOMIC_ACQUIRE, __HIP_MEMORY_SCOPE_AGENT) < NBLK)
            __builtin_amdgcn_s_sleep(2);
    }
    __syncthreads();
    __threadfence();             // acquire: invalidate stale L1/L2 before reading peers' data
}

// One GCN aggregation for 3 rows i0..i0+2: gs[r][k] = relu(dinv[i]*(sum_j adj[i,j]*tin[j,k] + tin[i,k]))
// j split 8 ways across thread groups (96 j each); tin read from L2 (393 KB, resident).
__device__ __forceinline__ void gcn_gs(SMem& sm, const float* __restrict__ adj,
                                       const float* __restrict__ tin,
                                       const float* __restrict__ dinv, int i0, int tid) {
    for (int idx = tid; idx < 3 * NN; idx += 256) {      // stage adj rows transposed: adjT[j][r]
        int r = idx / NN, j = idx - r * NN;
        sm.s2.adjT[j][r] = adj[(i0 + r) * NN + j];
    }
    __syncthreads();
    int k4 = tid & 31, jc = tid >> 5;                    // 4 k-values, 1/8th of j-range
    float4 a0 = {0,0,0,0}, a1 = {0,0,0,0}, a2 = {0,0,0,0};
    const float* tbase = tin + k4 * 4;
#pragma unroll 4
    for (int jj = 0; jj < 96; ++jj) {
        int j = jc * 96 + jj;
        float4 av = *(float4*)&sm.s2.adjT[j][0];         // broadcast read (uniform per half-wave)
        float4 tv = *(const float4*)&tbase[j * HD];      // coalesced 512B per half-wave, L2-hit
        fma4(a0, av.x, tv);
        fma4(a1, av.y, tv);
        fma4(a2, av.z, tv);
    }
    *(float4*)&sm.s2.part[jc][0][k4 * 4] = a0;
    *(float4*)&sm.s2.part[jc][1][k4 * 4] = a1;
    *(float4*)&sm.s2.part[jc][2][k4 * 4] = a2;
    __syncthreads();
    for (int idx = tid; idx < 3 * HD; idx += 256) {
        int r = idx >> 7, k = idx & 127;
        float s = tin[(i0 + r) * HD + k];                // self loop (adj+I)
#pragma unroll
        for (int c = 0; c < 8; ++c) s += sm.s2.part[c][r][k];
        sm.s2.gs[r][k] = relu(dinv[i0 + r] * s);
    }
    __syncthreads();
}

__global__ __launch_bounds__(256, 2) void fused(
        const float* __restrict__ x, const float* __restrict__ adj,
        const float* __restrict__ w1, const float* __restrict__ w2,
        const float* __restrict__ temb, const float* __restrict__ we1,
        const float* __restrict__ be1, const float* __restrict__ we2,
        const float* __restrict__ be2, const int* __restrict__ tptr,
        float* __restrict__ ws, float* __restrict__ out) {
    __shared__ SMem sm;
    int b = blockIdx.x, tid = threadIdx.x;
    int* cnt = (int*)ws;                 // 4 ints, zeroed by hipMemsetAsync
    float* dinv = ws + 16;               // 768
    float* cvec = ws + 800;              // 128
    float* t1 = ws + 1024;               // 768*128
    float* t2 = t1 + NN * HD;
    float* p  = t2 + NN * HD;
    float* q  = p + NN * HD;

    // ---- Stage 1: dinv, t1 = dinv*(x@w1) (blocks 0..255, 3 rows each); cvec (block 256) ----
    if (b < 256) {
        int i0 = 3 * b;
        for (int idx = tid; idx < 192; idx += 256) {     // x rows -> LDS
            int r = idx >> 6, c4 = idx & 63;
            *(float4*)&sm.s1.xs[r][c4 * 4] = *(const float4*)&x[(i0 + r) * FD + c4 * 4];
        }
        int wv = tid >> 6, ln = tid & 63;                // waves 0..2 sum one adj row each
        if (wv < 3) {
            const float4* ar = (const float4*)&adj[(i0 + wv) * NN];
            float4 A0 = ar[ln], A1 = ar[ln + 64], A2 = ar[ln + 128];
            float s = ((A0.x + A0.y) + (A0.z + A0.w)) + ((A1.x + A1.y) + (A1.z + A1.w))
                    + ((A2.x + A2.y) + (A2.z + A2.w));
#pragma unroll
            for (int off = 32; off > 0; off >>= 1) s += __shfl_down(s, off, 64);
            if (ln == 0) sm.s1.sdi[wv] = rsqrtf(s + 1.f);
        }
        __syncthreads();
        if (tid < 3) dinv[i0 + tid] = sm.s1.sdi[tid];
        int k = tid & 127, mh = tid >> 7;                // x@w1: k-col per thread, K split in 2
        float ac0 = 0.f, ac1 = 0.f, ac2 = 0.f;
        const float* wcol = w1 + k;
#pragma unroll 4
        for (int m = mh * 128; m < mh * 128 + 128; ++m) {
            float wval = wcol[m * HD];                   // coalesced; w1 read once per block (L2)
            ac0 = fmaf(sm.s1.xs[0][m], wval, ac0);
            ac1 = fmaf(sm.s1.xs[1][m], wval, ac1);
            ac2 = fmaf(sm.s1.xs[2][m], wval, ac2);
        }
        __syncthreads();
        float* tmp = &sm.s1.xs[0][0];                    // reuse xs (768 floats) for halves
        tmp[mh * 384 + 0 * 128 + k] = ac0;
        tmp[mh * 384 + 1 * 128 + k] = ac1;
        tmp[mh * 384 + 2 * 128 + k] = ac2;
        __syncthreads();
        for (int idx = tid; idx < 384; idx += 256) {
            int r = idx >> 7, kk = idx & 127;
            t1[(i0 + r) * HD + kk] = sm.s1.sdi[r] * (tmp[r * 128 + kk] + tmp[384 + r * 128 + kk]);
        }
    } else if (b == 256) {                               // cvec = temb[t]@we1[2H:] + be1
        if (tid < HD) sm.s1.ts[tid] = temb[tptr[0] * HD + tid];
        __syncthreads();
        if (tid < HD) {
            float a = be1[tid];
#pragma unroll 4
            for (int m = 0; m < HD; ++m)
                a = fmaf(sm.s1.ts[m], we1[(2 * HD + m) * HD + tid], a);
            cvec[tid] = a;
        }
    }
    gsync(&cnt[0]);

    // ---- Stage 2: g1 = relu(dinv*(A@t1)); t2 = dinv*(g1@w2) ----
    if (b < 256) {
        int i0 = 3 * b;
        gcn_gs(sm, adj, t1, dinv, i0, tid);
        for (int idx = tid; idx < 3 * HD; idx += 256) {
            int r = idx >> 7, k = idx & 127;
            float acc = 0.f;
            const float* wc = w2 + k;
#pragma unroll
            for (int m4 = 0; m4 < 32; ++m4) {
                float4 gv = *(float4*)&sm.s2.gs[r][m4 * 4];   // broadcast
                acc = fmaf(gv.x, wc[(m4 * 4 + 0) * HD], acc);
                acc = fmaf(gv.y, wc[(m4 * 4 + 1) * HD], acc);
                acc = fmaf(gv.z, wc[(m4 * 4 + 2) * HD], acc);
                acc = fmaf(gv.w, wc[(m4 * 4 + 3) * HD], acc);
            }
            t2[(i0 + r) * HD + k] = dinv[i0 + r] * acc;
        }
    }
    gsync(&cnt[1]);

    // ---- Stage 3: g2 = relu(dinv*(A@t2)); p = g2@we1[:H]+cvec, q = g2@we1[H:2H] ----
    if (b < 256) {
        int i0 = 3 * b;
        gcn_gs(sm, adj, t2, dinv, i0, tid);
        for (int idx = tid; idx < 3 * HD; idx += 256) {
            int r = idx >> 7, k = idx & 127;
            float ap = 0.f, aq = 0.f;
            const float* wp = we1 + k;
            const float* wq = we1 + HD * HD + k;
#pragma unroll
            for (int m4 = 0; m4 < 32; ++m4) {
                float4 gv = *(float4*)&sm.s2.gs[r][m4 * 4];
                ap = fmaf(gv.x, wp[(m4 * 4 + 0) * HD], ap); aq = fmaf(gv.x, wq[(m4 * 4 + 0) * HD], aq);
                ap = fmaf(gv.y, wp[(m4 * 4 + 1) * HD], ap); aq = fmaf(gv.y, wq[(m4 * 4 + 1) * HD], aq);
                ap = fmaf(gv.z, wp[(m4 * 4 + 2) * HD], ap); aq = fmaf(gv.z, wq[(m4 * 4 + 2) * HD], aq);
                ap = fmaf(gv.w, wp[(m4 * 4 + 3) * HD], ap); aq = fmaf(gv.w, wq[(m4 * 4 + 3) * HD], aq);
            }
            p[(i0 + r) * HD + k] = ap + cvec[k];
            q[(i0 + r) * HD + k] = aq;
        }
    }
    gsync(&cnt[2]);

    // ---- Stage 4: pair tiles (exactly 300 = grid size) ----
    {
        int t = b;
        int bj = (int)((sqrtf(8.f * t + 1.f) - 1.f) * 0.5f);
        while ((bj + 1) * (bj + 2) / 2 <= t) ++bj;
        while (bj * (bj + 1) / 2 > t) --bj;
        int bi = t - bj * (bj + 1) / 2;
        int i0 = bi * 32, j0 = bj * 32;
        int tx = tid & 15, ty = tid >> 4;
        if (tid < HD) sm.s4.w2s[tid] = we2[tid];
        float accij[2][2] = {{0.f, 0.f}, {0.f, 0.f}};
        float accji[2][2] = {{0.f, 0.f}, {0.f, 0.f}};
        for (int h = 0; h < 2; ++h) {
            __syncthreads();
            int kb = h * 64;
            for (int idx = tid; idx < 512; idx += 256) {
                int r = idx >> 4, c4 = idx & 15;
                *(float4*)&sm.s4.pi[r][c4 * 4] = *(const float4*)&p[(i0 + r) * HD + kb + c4 * 4];
                *(float4*)&sm.s4.qi[r][c4 * 4] = *(const float4*)&q[(i0 + r) * HD + kb + c4 * 4];
                *(float4*)&sm.s4.pj[r][c4 * 4] = *(const float4*)&p[(j0 + r) * HD + kb + c4 * 4];
                *(float4*)&sm.s4.qj[r][c4 * 4] = *(const float4*)&q[(j0 + r) * HD + kb + c4 * 4];
            }
            __syncthreads();
#pragma unroll 8
            for (int k4 = 0; k4 < 16; ++k4) {
                float4 w = *(float4*)&sm.s4.w2s[kb + k4 * 4];
                float4 Pi0 = *(float4*)&sm.s4.pi[2 * ty + 0][k4 * 4];
                float4 Pi1 = *(float4*)&sm.s4.pi[2 * ty + 1][k4 * 4];
                float4 Qi0 = *(float4*)&sm.s4.qi[2 * ty + 0][k4 * 4];
                float4 Qi1 = *(float4*)&sm.s4.qi[2 * ty + 1][k4 * 4];
                float4 Pj0 = *(float4*)&sm.s4.pj[2 * tx + 0][k4 * 4];
                float4 Pj1 = *(float4*)&sm.s4.pj[2 * tx + 1][k4 * 4];
                float4 Qj0 = *(float4*)&sm.s4.qj[2 * tx + 0][k4 * 4];
                float4 Qj1 = *(float4*)&sm.s4.qj[2 * tx + 1][k4 * 4];
                accij[0][0] += rdot(Pi0, Qj0, w); accji[0][0] += rdot(Pj0, Qi0, w);
                accij[0][1] += rdot(Pi0, Qj1, w); accji[0][1] += rdot(Pj1, Qi0, w);
                accij[1][0] += rdot(Pi1, Qj0, w); accji[1][0] += rdot(Pj0, Qi1, w);
                accij[1][1] += rdot(Pi1, Qj1, w); accji[1][1] += rdot(Pj1, Qi1, w);
            }
        }
        float bias = be2[0];
#pragma unroll
        for (int e = 0; e < 2; ++e)
#pragma unroll
            for (int f = 0; f < 2; ++f) {
                int i = i0 + 2 * ty + e, j = j0 + 2 * tx + f;
                float lij = accij[e][f] + bias, lji = accji[e][f] + bias;
                float v = 0.5f * (1.f / (1.f + __expf(-lij)) + 1.f / (1.f + __expf(-lji)));
                out[i * NN + j] = v;
                out[j * NN + i] = v;
            }
    }
}

extern "C" void kernel_launch(void* const* d_in, const int* in_sizes, int n_in,
                              void* d_out, int out_size, void* d_ws, size_t ws_size,
                              hipStream_t stream) {
    const float* x    = (const float*)d_in[0];
    const float* adj  = (const float*)d_in[1];
    const float* w1   = (const float*)d_in[2];
    const float* w2   = (const float*)d_in[3];
    const float* temb = (const float*)d_in[4];
    const float* we1  = (const float*)d_in[5];
    const float* be1  = (const float*)d_in[6];
    const float* we2  = (const float*)d_in[7];
    const float* be2  = (const float*)d_in[8];
    const int* tptr   = (const int*)d_in[9];
    float* out        = (float*)d_out;
    float* ws         = (float*)d_ws;

    // zero the 4 barrier counters (captured into the graph, re-runs every replay)
    hipMemsetAsync(d_ws, 0, 16, stream);
    fused<<<NBLK, 256, 0, stream>>>(x, adj, w1, w2, temb, we1, be1, we2, be2, tptr, ws, out);
}

// Round 2
// 126.408 us; speedup vs baseline: 3.2245x; 3.2245x over previous
//
#include <hip/hip_runtime.h>

#define NN 768
#define FD 256
#define HD 128

__device__ __forceinline__ float relu(float x) { return x > 0.f ? x : 0.f; }
__device__ __forceinline__ void fma4(float4& a, float s, float4 v) {
    a.x = fmaf(s, v.x, a.x); a.y = fmaf(s, v.y, a.y);
    a.z = fmaf(s, v.z, a.z); a.w = fmaf(s, v.w, a.w);
}
__device__ __forceinline__ float rdot(float4 a, float4 b, float4 w) {
    float s = relu(a.x + b.x) * w.x;
    s = fmaf(relu(a.y + b.y), w.y, s);
    s = fmaf(relu(a.z + b.z), w.z, s);
    s = fmaf(relu(a.w + b.w), w.w, s);
    return s;
}

// K1: blocks 0..255 (768 thr): rows 3b..3b+2 -> dinv[i], t1 = dinv*(x@w1)
//     block 256: cvec[k] = temb[t]@we1[2H:] + be1   (unchanged from baseline)
__global__ __launch_bounds__(768) void k_prep(
        const float* __restrict__ x, const float* __restrict__ adj,
        const float* __restrict__ w1, const float* __restrict__ temb,
        const float* __restrict__ we1, const float* __restrict__ be1,
        const int* __restrict__ tptr, float* __restrict__ dinv,
        float* __restrict__ cvec, float* __restrict__ t1D) {
    int b = blockIdx.x, tid = threadIdx.x;
    if (b == 256) {
        __shared__ float ts[HD];
        if (tid < HD) ts[tid] = temb[tptr[0] * HD + tid];
        __syncthreads();
        if (tid < HD) {
            float a0 = be1[tid], a1 = 0.f, a2 = 0.f, a3 = 0.f;
            for (int m = 0; m < HD; m += 4) {
                a0 = fmaf(ts[m + 0], we1[(2 * HD + m + 0) * HD + tid], a0);
                a1 = fmaf(ts[m + 1], we1[(2 * HD + m + 1) * HD + tid], a1);
                a2 = fmaf(ts[m + 2], we1[(2 * HD + m + 2) * HD + tid], a2);
                a3 = fmaf(ts[m + 3], we1[(2 * HD + m + 3) * HD + tid], a3);
            }
            cvec[tid] = (a0 + a1) + (a2 + a3);
        }
        return;
    }
    int i0 = b * 3;
    __shared__ float xs[3][FD];
    __shared__ float part[3][2][HD];
    __shared__ float red[12];
    __shared__ float sdi[3];
    if (tid < 192) {
        int row = tid >> 6, m4 = tid & 63;
        *(float4*)&xs[row][m4 * 4] = *(const float4*)&x[(i0 + row) * FD + m4 * 4];
    }
    {
        int r2 = tid >> 8, s = tid & 255;
        float sum = 0.f;
        if (s < 192) {
            float4 a = *(const float4*)&adj[(i0 + r2) * NN + s * 4];
            sum = (a.x + a.y) + (a.z + a.w);
        }
#pragma unroll
        for (int off = 32; off > 0; off >>= 1) sum += __shfl_down(sum, off, 64);
        if ((tid & 63) == 0) red[tid >> 6] = sum;
    }
    __syncthreads();
    if (tid < 3) {
        float t = (red[4 * tid] + red[4 * tid + 1]) + (red[4 * tid + 2] + red[4 * tid + 3]);
        float d = rsqrtf(t + 1.f);
        sdi[tid] = d; dinv[i0 + tid] = d;
    }
    __syncthreads();
    int r = tid >> 8, half = (tid >> 7) & 1, k = tid & 127;
    float a0 = 0.f, a1 = 0.f, a2 = 0.f, a3 = 0.f;
    for (int g = 128 * half; g < 128 * half + 128; g += 16) {
        float wv[16];
#pragma unroll
        for (int u = 0; u < 16; ++u) wv[u] = w1[(g + u) * HD + k];
#pragma unroll
        for (int u = 0; u < 16; ++u) {
            float xv = xs[r][g + u];
            if ((u & 3) == 0) a0 = fmaf(xv, wv[u], a0);
            else if ((u & 3) == 1) a1 = fmaf(xv, wv[u], a1);
            else if ((u & 3) == 2) a2 = fmaf(xv, wv[u], a2);
            else a3 = fmaf(xv, wv[u], a3);
        }
    }
    part[r][half][k] = (a0 + a1) + (a2 + a3);
    __syncthreads();
    if (half == 0) t1D[(i0 + r) * HD + k] = sdi[r] * (part[r][0][k] + part[r][1][k]);
}

// Full-K GCN aggregation for 3 rows: gs[r][k] = relu(dinv[i]*(sum_j adj[i,j]*tin[j,k] + tin[i,k]))
// Separate a0/a1/a2 LDS arrays: conflict-free stage writes, broadcast reads.
// tin (393 KB) streamed from L2; 8 j-chunks x 32 k4-threads, partial reduce in LDS.
__device__ __forceinline__ void gcn_agg(
        float* __restrict__ a0s, float* __restrict__ a1s, float* __restrict__ a2s,
        float (*part)[3][HD], float (*gs)[HD],
        const float* __restrict__ adj, const float* __restrict__ tin,
        const float* __restrict__ dinv, int i0, int tid) {
    for (int j = tid; j < NN; j += 256) {
        a0s[j] = adj[(i0 + 0) * NN + j];
        a1s[j] = adj[(i0 + 1) * NN + j];
        a2s[j] = adj[(i0 + 2) * NN + j];
    }
    __syncthreads();
    int k4 = tid & 31, jc = tid >> 5;
    float4 acc0 = {0,0,0,0}, acc1 = {0,0,0,0}, acc2 = {0,0,0,0};
    const float* tb = tin + k4 * 4;
#pragma unroll 4
    for (int jj = 0; jj < 96; ++jj) {
        int j = jc * 96 + jj;
        float4 tv = *(const float4*)&tb[j * HD];   // 512B contiguous per 32-lane group, L2-hit
        fma4(acc0, a0s[j], tv);                    // LDS broadcast (uniform per group)
        fma4(acc1, a1s[j], tv);
        fma4(acc2, a2s[j], tv);
    }
    *(float4*)&part[jc][0][k4 * 4] = acc0;
    *(float4*)&part[jc][1][k4 * 4] = acc1;
    *(float4*)&part[jc][2][k4 * 4] = acc2;
    __syncthreads();
    for (int idx = tid; idx < 3 * HD; idx += 256) {
        int r = idx >> 7, k = idx & 127;
        float s = tin[(i0 + r) * HD + k];          // self loop (adj + I)
#pragma unroll
        for (int c = 0; c < 8; ++c) s += part[c][r][k];
        gs[r][k] = relu(dinv[i0 + r] * s);
    }
    __syncthreads();
}

// K2: g1 = relu(dinv*(A@t1)); t2 = dinv*(g1@w2).  256 blocks x 256 thr, 3 rows each.
__global__ __launch_bounds__(256) void k_layer1(
        const float* __restrict__ adj, const float* __restrict__ t1,
        const float* __restrict__ dinv, const float* __restrict__ w2,
        float* __restrict__ t2) {
    __shared__ float a0s[NN], a1s[NN], a2s[NN];
    __shared__ float part[8][3][HD];
    __shared__ float gs[3][HD];
    int tid = threadIdx.x, i0 = blockIdx.x * 3;
    gcn_agg(a0s, a1s, a2s, part, gs, adj, t1, dinv, i0, tid);
    for (int idx = tid; idx < 3 * HD; idx += 256) {
        int r = idx >> 7, k = idx & 127;
        float acc = 0.f;
        const float* wc = w2 + k;
#pragma unroll
        for (int m4 = 0; m4 < 32; ++m4) {
            float4 gv = *(float4*)&gs[r][m4 * 4];  // LDS broadcast
            acc = fmaf(gv.x, wc[(m4 * 4 + 0) * HD], acc);
            acc = fmaf(gv.y, wc[(m4 * 4 + 1) * HD], acc);
            acc = fmaf(gv.z, wc[(m4 * 4 + 2) * HD], acc);
            acc = fmaf(gv.w, wc[(m4 * 4 + 3) * HD], acc);
        }
        t2[(i0 + r) * HD + k] = dinv[i0 + r] * acc;
    }
}

// K3: g2 = relu(dinv*(A@t2)); p = g2@we1[:H]+cvec, q = g2@we1[H:2H].
__global__ __launch_bounds__(256) void k_layer2(
        const float* __restrict__ adj, const float* __restrict__ t2,
        const float* __restrict__ dinv, const float* __restrict__ we1,
        const float* __restrict__ cvec, float* __restrict__ p, float* __restrict__ q) {
    __shared__ float a0s[NN], a1s[NN], a2s[NN];
    __shared__ float part[8][3][HD];
    __shared__ float gs[3][HD];
    int tid = threadIdx.x, i0 = blockIdx.x * 3;
    gcn_agg(a0s, a1s, a2s, part, gs, adj, t2, dinv, i0, tid);
    for (int idx = tid; idx < 3 * HD; idx += 256) {
        int r = idx >> 7, k = idx & 127;
        float ap = 0.f, aq = 0.f;
        const float* wp = we1 + k;
        const float* wq = we1 + HD * HD + k;
#pragma unroll
        for (int m4 = 0; m4 < 32; ++m4) {
            float4 gv = *(float4*)&gs[r][m4 * 4];
            ap = fmaf(gv.x, wp[(m4 * 4 + 0) * HD], ap); aq = fmaf(gv.x, wq[(m4 * 4 + 0) * HD], aq);
            ap = fmaf(gv.y, wp[(m4 * 4 + 1) * HD], ap); aq = fmaf(gv.y, wq[(m4 * 4 + 1) * HD], aq);
            ap = fmaf(gv.z, wp[(m4 * 4 + 2) * HD], ap); aq = fmaf(gv.z, wq[(m4 * 4 + 2) * HD], aq);
            ap = fmaf(gv.w, wp[(m4 * 4 + 3) * HD], ap); aq = fmaf(gv.w, wq[(m4 * 4 + 3) * HD], aq);
        }
        p[(i0 + r) * HD + k] = ap + cvec[k];
        q[(i0 + r) * HD + k] = aq;
    }
}

// K4: 32x32 tile pairs (bi<=bj), 300 blocks, 256 thr, 2x2 per thread. (baseline)
__global__ __launch_bounds__(256) void k_pair(
        const float* __restrict__ p, const float* __restrict__ q,
        const float* __restrict__ we2, const float* __restrict__ be2,
        float* __restrict__ out) {
    int t = blockIdx.x;
    int bj = (int)((sqrtf(8.f * t + 1.f) - 1.f) * 0.5f);
    while ((bj + 1) * (bj + 2) / 2 <= t) ++bj;
    while (bj * (bj + 1) / 2 > t) --bj;
    int bi = t - bj * (bj + 1) / 2;
    int i0 = bi * 32, j0 = bj * 32;
    __shared__ float spi[32][68], sqi[32][68], spj[32][68], sqj[32][68];
    __shared__ float w2s[HD];
    int tid = threadIdx.x;
    int tx = tid & 15, ty = tid >> 4;
    if (tid < HD) w2s[tid] = we2[tid];
    float accij[2][2] = {{0.f, 0.f}, {0.f, 0.f}};
    float accji[2][2] = {{0.f, 0.f}, {0.f, 0.f}};
    for (int h = 0; h < 2; ++h) {
        __syncthreads();
        int kb = h * 64;
        for (int idx = tid; idx < 512; idx += 256) {
            int r = idx >> 4, c4 = idx & 15;
            *(float4*)&spi[r][c4 * 4] = *(const float4*)&p[(i0 + r) * HD + kb + c4 * 4];
            *(float4*)&sqi[r][c4 * 4] = *(const float4*)&q[(i0 + r) * HD + kb + c4 * 4];
            *(float4*)&spj[r][c4 * 4] = *(const float4*)&p[(j0 + r) * HD + kb + c4 * 4];
            *(float4*)&sqj[r][c4 * 4] = *(const float4*)&q[(j0 + r) * HD + kb + c4 * 4];
        }
        __syncthreads();
#pragma unroll 8
        for (int k4 = 0; k4 < 16; ++k4) {
            float4 w = *(float4*)&w2s[kb + k4 * 4];
            float4 Pi0 = *(float4*)&spi[2 * ty + 0][k4 * 4];
            float4 Pi1 = *(float4*)&spi[2 * ty + 1][k4 * 4];
            float4 Qi0 = *(float4*)&sqi[2 * ty + 0][k4 * 4];
            float4 Qi1 = *(float4*)&sqi[2 * ty + 1][k4 * 4];
            float4 Pj0 = *(float4*)&spj[2 * tx + 0][k4 * 4];
            float4 Pj1 = *(float4*)&spj[2 * tx + 1][k4 * 4];
            float4 Qj0 = *(float4*)&sqj[2 * tx + 0][k4 * 4];
            float4 Qj1 = *(float4*)&sqj[2 * tx + 1][k4 * 4];
            accij[0][0] += rdot(Pi0, Qj0, w); accji[0][0] += rdot(Pj0, Qi0, w);
            accij[0][1] += rdot(Pi0, Qj1, w); accji[0][1] += rdot(Pj1, Qi0, w);
            accij[1][0] += rdot(Pi1, Qj0, w); accji[1][0] += rdot(Pj0, Qi1, w);
            accij[1][1] += rdot(Pi1, Qj1, w); accji[1][1] += rdot(Pj1, Qi1, w);
        }
    }
    float bias = be2[0];
#pragma unroll
    for (int e = 0; e < 2; ++e)
#pragma unroll
        for (int f = 0; f < 2; ++f) {
            int i = i0 + 2 * ty + e, j = j0 + 2 * tx + f;
            float lij = accij[e][f] + bias, lji = accji[e][f] + bias;
            float v = 0.5f * (1.f / (1.f + __expf(-lij)) + 1.f / (1.f + __expf(-lji)));
            out[i * NN + j] = v;
            out[j * NN + i] = v;
        }
}

extern "C" void kernel_launch(void* const* d_in, const int* in_sizes, int n_in,
                              void* d_out, int out_size, void* d_ws, size_t ws_size,
                              hipStream_t stream) {
    const float* x    = (const float*)d_in[0];
    const float* adj  = (const float*)d_in[1];
    const float* w1   = (const float*)d_in[2];
    const float* w2   = (const float*)d_in[3];
    const float* temb = (const float*)d_in[4];
    const float* we1  = (const float*)d_in[5];
    const float* be1  = (const float*)d_in[6];
    const float* we2  = (const float*)d_in[7];
    const float* be2  = (const float*)d_in[8];
    const int* tptr   = (const int*)d_in[9];
    float* out        = (float*)d_out;

    float* ws   = (float*)d_ws;
    float* dinv = ws;               // 768
    float* cvec = ws + 768;         // 128
    float* t1   = ws + 1024;        // 768*128
    float* t2   = t1 + NN * HD;
    float* p    = t2 + NN * HD;
    float* q    = p + NN * HD;

    k_prep  <<<257, 768, 0, stream>>>(x, adj, w1, temb, we1, be1, tptr, dinv, cvec, t1);
    k_layer1<<<256, 256, 0, stream>>>(adj, t1, dinv, w2, t2);
    k_layer2<<<256, 256, 0, stream>>>(adj, t2, dinv, we1, cvec, p, q);
    k_pair  <<<300, 256, 0, stream>>>(p, q, we2, be2, out);
}